// Round 4
// baseline (12014.027 us; speedup 1.0000x reference)
//
#include <hip/hip_runtime.h>
#include <math.h>

#define B_  1024
#define T_  512
#define D_  30
#define H1_ 96
#define G1_ 384
#define H2_ 64
#define G2_ 256

// Inter-kernel buffers as device globals (.bss, bound at module load).
// Fully overwritten every call before being read (no cross-call state).
__device__ float g_h1[(size_t)B_ * T_ * 192];   // 384 MiB: layer-1 output
__device__ float g_h2f[(size_t)B_ * H2_];       // layer-2 fwd final state

__device__ __forceinline__ float fast_tanh(float v) {
  float a = fabsf(v);
  float e = __expf(-2.0f * a);
  float t = 1.0f - 2.0f * e / (1.0f + e);
  return v < 0.0f ? -t : t;
}
__device__ __forceinline__ float fast_sigmoid(float v) {
  return 0.5f + 0.5f * fast_tanh(0.5f * v);   // exact identity, overflow-safe
}

#define REP8(M) M(0) M(1) M(2) M(3) M(4) M(5) M(6) M(7)

// ---------------------------------------------------------------------------
// Layer 1: bidirectional LSTM over x (B,T,30) -> g_h1 (B,T,192)
// grid (256, 2): 4 batches/block, dir = blockIdx.y. 768 threads:
// (gate-pair p = tid%192 -> gates p and p+192, K-quarter q = tid/192).
// Each thread: 2 gates x 32 k in 16 named float4 (2 gates amortize each
// v-broadcast: per-CU DS reads drop 1536 -> 384/step vs round 3).
// Unified v[128]: [0:30)=x_t, [30:32)=0, [32:128)=h_{t-1}.
// q is wave-uniform (192 = 3 waves) -> all hx reads are broadcasts.
// ---------------------------------------------------------------------------
__global__ __launch_bounds__(768, 3)
void lstm1_kernel(const float* __restrict__ x,
                  const float* __restrict__ Wih_f, const float* __restrict__ Whh_f,
                  const float* __restrict__ bih_f, const float* __restrict__ bhh_f,
                  const float* __restrict__ Wih_b, const float* __restrict__ Whh_b,
                  const float* __restrict__ bih_b, const float* __restrict__ bhh_b)
{
  const int tid = threadIdx.x;
  const int dir = blockIdx.y;
  const int b0  = blockIdx.x * 4;

  const float* __restrict__ Wih = dir ? Wih_b : Wih_f;
  const float* __restrict__ Whh = dir ? Whh_b : Whh_f;
  const float* __restrict__ bih = dir ? bih_b : bih_f;
  const float* __restrict__ bhh = dir ? bhh_b : bhh_f;

  __shared__ __align__(16) float hx[4][128];     // [b][0:30 x | 32:128 h]
  __shared__ float gbuf[G1_ * 17];               // [gate][q*4+b], stride 17

  const int p = tid % 192;                       // gate pair: g0=p, g1=p+192
  const int q = tid / 192;                       // K-quarter, wave-uniform
  const int g0 = p, g1 = p + 192;

  float4 wa0,wa1,wa2,wa3,wa4,wa5,wa6,wa7;        // gate g0, k=32q..32q+32
  float4 wb0,wb1,wb2,wb3,wb4,wb5,wb6,wb7;        // gate g1
  if (q == 0) {                                  // k 0..31: x-part (30 + 2 zeros)
    const float* A  = Wih + g0 * D_;
    const float* Bp = Wih + g1 * D_;
#define LQ0(i) \
    wa##i = make_float4(A[4*i],  A[4*i+1],  (4*i+2 < 30) ? A[4*i+2]  : 0.f, \
                        (4*i+3 < 30) ? A[4*i+3]  : 0.f); \
    wb##i = make_float4(Bp[4*i], Bp[4*i+1], (4*i+2 < 30) ? Bp[4*i+2] : 0.f, \
                        (4*i+3 < 30) ? Bp[4*i+3] : 0.f);
    REP8(LQ0)
#undef LQ0
  } else {                                       // k 32q..32q+32 -> h[32(q-1)..]
    const float4* A  = (const float4*)(Whh + g0 * H1_ + 32 * (q - 1));
    const float4* Bp = (const float4*)(Whh + g1 * H1_ + 32 * (q - 1));
#define LQH(i) wa##i = A[i]; wb##i = Bp[i];
    REP8(LQH)
#undef LQH
  }

  // updaters: tid < 384 -> (unit uj, batch ub)
  const int uj = tid % 96;
  const int ub = (tid / 96) & 3;
  const float bias_i = bih[uj      ] + bhh[uj      ];
  const float bias_f = bih[uj +  96] + bhh[uj +  96];
  const float bias_g = bih[uj + 192] + bhh[uj + 192];
  const float bias_o = bih[uj + 288] + bhh[uj + 288];
  float c_state = 0.0f;

  for (int i = tid; i < 4 * 128; i += 768) (&hx[0][0])[i] = 0.0f;
  __syncthreads();
  const int xb = tid / 30;
  const int xd = tid - xb * 30;
  if (tid < 120) {
    const int t0 = dir ? (T_ - 1) : 0;
    hx[xb][xd] = x[((size_t)(b0 + xb) * T_ + t0) * D_ + xd];
  }
  __syncthreads();

  const int koff = q * 8;                        // float4 offset into v[128]
  const float4* hx4 = (const float4*)(&hx[0][0]);

  for (int s = 0; s < T_; ++s) {
    const int t = dir ? (T_ - 1 - s) : s;
    float xn = 0.0f;
    if (tid < 120 && s + 1 < T_) {
      const int tn = dir ? (t - 1) : (t + 1);
      xn = x[((size_t)(b0 + xb) * T_ + tn) * D_ + xd];
    }
    float a00 = 0.f, a01 = 0.f, a02 = 0.f, a03 = 0.f;   // gate g0 x batch
    float a10 = 0.f, a11 = 0.f, a12 = 0.f, a13 = 0.f;   // gate g1 x batch
#define FB1(i) { \
    float4 v0 = hx4[0*32 + koff + i]; float4 v1 = hx4[1*32 + koff + i]; \
    float4 v2 = hx4[2*32 + koff + i]; float4 v3 = hx4[3*32 + koff + i]; \
    a00 = fmaf(wa##i.x, v0.x, a00); a00 = fmaf(wa##i.y, v0.y, a00); \
    a00 = fmaf(wa##i.z, v0.z, a00); a00 = fmaf(wa##i.w, v0.w, a00); \
    a01 = fmaf(wa##i.x, v1.x, a01); a01 = fmaf(wa##i.y, v1.y, a01); \
    a01 = fmaf(wa##i.z, v1.z, a01); a01 = fmaf(wa##i.w, v1.w, a01); \
    a02 = fmaf(wa##i.x, v2.x, a02); a02 = fmaf(wa##i.y, v2.y, a02); \
    a02 = fmaf(wa##i.z, v2.z, a02); a02 = fmaf(wa##i.w, v2.w, a02); \
    a03 = fmaf(wa##i.x, v3.x, a03); a03 = fmaf(wa##i.y, v3.y, a03); \
    a03 = fmaf(wa##i.z, v3.z, a03); a03 = fmaf(wa##i.w, v3.w, a03); \
    a10 = fmaf(wb##i.x, v0.x, a10); a10 = fmaf(wb##i.y, v0.y, a10); \
    a10 = fmaf(wb##i.z, v0.z, a10); a10 = fmaf(wb##i.w, v0.w, a10); \
    a11 = fmaf(wb##i.x, v1.x, a11); a11 = fmaf(wb##i.y, v1.y, a11); \
    a11 = fmaf(wb##i.z, v1.z, a11); a11 = fmaf(wb##i.w, v1.w, a11); \
    a12 = fmaf(wb##i.x, v2.x, a12); a12 = fmaf(wb##i.y, v2.y, a12); \
    a12 = fmaf(wb##i.z, v2.z, a12); a12 = fmaf(wb##i.w, v2.w, a12); \
    a13 = fmaf(wb##i.x, v3.x, a13); a13 = fmaf(wb##i.y, v3.y, a13); \
    a13 = fmaf(wb##i.z, v3.z, a13); a13 = fmaf(wb##i.w, v3.w, a13); }
    REP8(FB1)
#undef FB1
    {
      const int e0 = g0 * 17 + q * 4;
      const int e1 = g1 * 17 + q * 4;
      gbuf[e0+0] = a00; gbuf[e0+1] = a01; gbuf[e0+2] = a02; gbuf[e0+3] = a03;
      gbuf[e1+0] = a10; gbuf[e1+1] = a11; gbuf[e1+2] = a12; gbuf[e1+3] = a13;
    }
    __syncthreads();
    if (tid < 120 && s + 1 < T_) hx[xb][xd] = xn;
    if (tid < 384) {
      float gi = bias_i, gf = bias_f, gg = bias_g, go = bias_o;
#pragma unroll
      for (int qq = 0; qq < 4; ++qq) {
        gi += gbuf[(uj      ) * 17 + qq * 4 + ub];
        gf += gbuf[(uj +  96) * 17 + qq * 4 + ub];
        gg += gbuf[(uj + 192) * 17 + qq * 4 + ub];
        go += gbuf[(uj + 288) * 17 + qq * 4 + ub];
      }
      float iv = fast_sigmoid(gi);
      float fv = fast_sigmoid(gf);
      float ov = fast_sigmoid(go);
      c_state = fv * c_state + iv * fast_tanh(gg);
      float h = ov * fast_tanh(c_state);
      hx[ub][32 + uj] = h;
      g_h1[((size_t)(b0 + ub) * T_ + t) * 192 + dir * 96 + uj] = h;
    }
    __syncthreads();
  }
}

// ---------------------------------------------------------------------------
// Layer 2 forward scan: g_h1 (B,T,192) -> g_h2f (B,64).
// grid 256: 4 batches/block. 1024 threads: (gate-pair p = tid&127 -> gates
// p and p+128, K-eighth q = tid>>7, K_own=32). v[256]: [0:192)=h1_t,
// [192:256)=h2_{t-1}. Per-CU DS reads: 1024 -> 512/step vs round 3.
// ---------------------------------------------------------------------------
__global__ __launch_bounds__(1024, 4)
void lstm2f_kernel(const float* __restrict__ Wih, const float* __restrict__ Whh,
                   const float* __restrict__ bih, const float* __restrict__ bhh)
{
  const int tid = threadIdx.x;
  const int b0  = blockIdx.x * 4;
  const int p   = tid & 127;                     // gate pair: g0=p, g1=p+128
  const int q   = tid >> 7;                      // K-eighth, wave-uniform
  const int g0 = p, g1 = p + 128;

  __shared__ __align__(16) float hx[4][256];     // [b][0:192 h1 | 192:256 h2prev]
  __shared__ float gbuf[G2_ * 33];               // [gate][q*4+b], stride 33

  float4 wa0,wa1,wa2,wa3,wa4,wa5,wa6,wa7;
  float4 wb0,wb1,wb2,wb3,wb4,wb5,wb6,wb7;
  {
    const float4* A  = (q < 6) ? (const float4*)(Wih + g0 * 192 + 32 * q)
                               : (const float4*)(Whh + g0 * H2_ + 32 * (q - 6));
    const float4* Bp = (q < 6) ? (const float4*)(Wih + g1 * 192 + 32 * q)
                               : (const float4*)(Whh + g1 * H2_ + 32 * (q - 6));
#define LQ2(i) wa##i = A[i]; wb##i = Bp[i];
    REP8(LQ2)
#undef LQ2
  }

  const int uj = tid & 63;                       // updaters: tid < 256
  const int ub = (tid >> 6) & 3;
  const float bias_i = bih[uj      ] + bhh[uj      ];
  const float bias_f = bih[uj +  64] + bhh[uj +  64];
  const float bias_g = bih[uj + 128] + bhh[uj + 128];
  const float bias_o = bih[uj + 192] + bhh[uj + 192];
  float c_state = 0.0f;

  for (int i = tid; i < 4 * 256; i += 1024) (&hx[0][0])[i] = 0.0f;
  __syncthreads();
  const int pb = tid / 96;                       // h1 stagers: tid < 384
  const int pj = tid - pb * 96;
  if (tid < 384) {
    *(float2*)&hx[pb][pj * 2] =
        *(const float2*)&g_h1[((size_t)(b0 + pb) * T_ + 0) * 192 + pj * 2];
  }
  __syncthreads();

  const int koff = q * 8;
  const float4* hx4 = (const float4*)(&hx[0][0]);

  for (int s = 0; s < T_; ++s) {
    float2 pre = make_float2(0.0f, 0.0f);
    if (tid < 384 && s + 1 < T_) {
      pre = *(const float2*)&g_h1[((size_t)(b0 + pb) * T_ + (s + 1)) * 192 + pj * 2];
    }
    float a00 = 0.f, a01 = 0.f, a02 = 0.f, a03 = 0.f;
    float a10 = 0.f, a11 = 0.f, a12 = 0.f, a13 = 0.f;
#define FB2(i) { \
    float4 v0 = hx4[0*64 + koff + i]; float4 v1 = hx4[1*64 + koff + i]; \
    float4 v2 = hx4[2*64 + koff + i]; float4 v3 = hx4[3*64 + koff + i]; \
    a00 = fmaf(wa##i.x, v0.x, a00); a00 = fmaf(wa##i.y, v0.y, a00); \
    a00 = fmaf(wa##i.z, v0.z, a00); a00 = fmaf(wa##i.w, v0.w, a00); \
    a01 = fmaf(wa##i.x, v1.x, a01); a01 = fmaf(wa##i.y, v1.y, a01); \
    a01 = fmaf(wa##i.z, v1.z, a01); a01 = fmaf(wa##i.w, v1.w, a01); \
    a02 = fmaf(wa##i.x, v2.x, a02); a02 = fmaf(wa##i.y, v2.y, a02); \
    a02 = fmaf(wa##i.z, v2.z, a02); a02 = fmaf(wa##i.w, v2.w, a02); \
    a03 = fmaf(wa##i.x, v3.x, a03); a03 = fmaf(wa##i.y, v3.y, a03); \
    a03 = fmaf(wa##i.z, v3.z, a03); a03 = fmaf(wa##i.w, v3.w, a03); \
    a10 = fmaf(wb##i.x, v0.x, a10); a10 = fmaf(wb##i.y, v0.y, a10); \
    a10 = fmaf(wb##i.z, v0.z, a10); a10 = fmaf(wb##i.w, v0.w, a10); \
    a11 = fmaf(wb##i.x, v1.x, a11); a11 = fmaf(wb##i.y, v1.y, a11); \
    a11 = fmaf(wb##i.z, v1.z, a11); a11 = fmaf(wb##i.w, v1.w, a11); \
    a12 = fmaf(wb##i.x, v2.x, a12); a12 = fmaf(wb##i.y, v2.y, a12); \
    a12 = fmaf(wb##i.z, v2.z, a12); a12 = fmaf(wb##i.w, v2.w, a12); \
    a13 = fmaf(wb##i.x, v3.x, a13); a13 = fmaf(wb##i.y, v3.y, a13); \
    a13 = fmaf(wb##i.z, v3.z, a13); a13 = fmaf(wb##i.w, v3.w, a13); }
    REP8(FB2)
#undef FB2
    {
      const int e0 = g0 * 33 + q * 4;
      const int e1 = g1 * 33 + q * 4;
      gbuf[e0+0] = a00; gbuf[e0+1] = a01; gbuf[e0+2] = a02; gbuf[e0+3] = a03;
      gbuf[e1+0] = a10; gbuf[e1+1] = a11; gbuf[e1+2] = a12; gbuf[e1+3] = a13;
    }
    __syncthreads();
    if (tid < 384 && s + 1 < T_) *(float2*)&hx[pb][pj * 2] = pre;
    if (tid < 256) {
      float gi = bias_i, gf = bias_f, gg = bias_g, go = bias_o;
#pragma unroll
      for (int qq = 0; qq < 8; ++qq) {
        gi += gbuf[(uj      ) * 33 + qq * 4 + ub];
        gf += gbuf[(uj +  64) * 33 + qq * 4 + ub];
        gg += gbuf[(uj + 128) * 33 + qq * 4 + ub];
        go += gbuf[(uj + 192) * 33 + qq * 4 + ub];
      }
      float iv = fast_sigmoid(gi), fv = fast_sigmoid(gf), ov = fast_sigmoid(go);
      c_state = fv * c_state + iv * fast_tanh(gg);
      float h = ov * fast_tanh(c_state);
      hx[ub][192 + uj] = h;
      if (s == T_ - 1) g_h2f[(b0 + ub) * H2_ + uj] = h;
    }
    __syncthreads();
  }
}

// ---------------------------------------------------------------------------
// Tail: layer-2 backward (ONE step from zero state on h1[:,T-1,:]) + dense
// head. grid 128 x 256 threads, 8 batch/block. (negligible runtime)
// ---------------------------------------------------------------------------
__global__ __launch_bounds__(256)
void tail_kernel(const float* __restrict__ Wih, const float* __restrict__ bih,
                 const float* __restrict__ bhh,
                 const float* __restrict__ W1, const float* __restrict__ b1,
                 const float* __restrict__ W2, const float* __restrict__ b2,
                 float* __restrict__ out)
{
  const int tid = threadIdx.x;
  const int b0  = blockIdx.x * 8;

  __shared__ __align__(16) float hl[8][192];    // h1 at t = T-1
  __shared__ float gb[G2_ * 9];
  __shared__ __align__(16) float last[8][128];  // [h2f | h2b]
  __shared__ float db[8][32];

  for (int i = tid; i < 8 * 96; i += 256) {
    int bb = i / 96, jj = i - (i / 96) * 96;
    *(float2*)&hl[bb][jj * 2] =
        *(const float2*)&g_h1[((size_t)(b0 + bb) * T_ + (T_ - 1)) * 192 + jj * 2];
  }
  for (int i = tid; i < 8 * 64; i += 256) {
    int bb = i >> 6, jj = i & 63;
    last[bb][jj] = g_h2f[(b0 + bb) * H2_ + jj];
  }
  __syncthreads();

  {
    const int gg_ = tid;
    const float* wr = Wih + gg_ * 192;
    const float bias = bih[gg_] + bhh[gg_];
    float acc[8];
#pragma unroll
    for (int b = 0; b < 8; ++b) acc[b] = bias;
#pragma unroll 4
    for (int qq = 0; qq < 48; ++qq) {
      float4 wv = *(const float4*)&wr[qq * 4];
#pragma unroll
      for (int b = 0; b < 8; ++b) {
        float4 v = *(const float4*)&hl[b][qq * 4];
        acc[b] = fmaf(wv.x, v.x, acc[b]);
        acc[b] = fmaf(wv.y, v.y, acc[b]);
        acc[b] = fmaf(wv.z, v.z, acc[b]);
        acc[b] = fmaf(wv.w, v.w, acc[b]);
      }
    }
#pragma unroll
    for (int b = 0; b < 8; ++b) gb[gg_ * 9 + b] = acc[b];
  }
  __syncthreads();

  for (int pp = tid; pp < 512; pp += 256) {
    int jj = pp & 63, bb = pp >> 6;
    float gi = gb[(jj      ) * 9 + bb];
    float gg = gb[(jj + 128) * 9 + bb];
    float go = gb[(jj + 192) * 9 + bb];
    float c  = fast_sigmoid(gi) * fast_tanh(gg);
    float h  = fast_sigmoid(go) * fast_tanh(c);
    last[bb][64 + jj] = h;
  }
  __syncthreads();

  {
    int u = tid & 31, bb = tid >> 5;
    const float* wr1 = W1 + u * 128;
    float a = b1[u];
#pragma unroll
    for (int qq = 0; qq < 32; ++qq) {
      float4 wv = *(const float4*)&wr1[qq * 4];
      float4 v  = *(const float4*)&last[bb][qq * 4];
      a = fmaf(wv.x, v.x, a); a = fmaf(wv.y, v.y, a);
      a = fmaf(wv.z, v.z, a); a = fmaf(wv.w, v.w, a);
    }
    db[bb][u] = fmaxf(a, 0.0f);
  }
  __syncthreads();

  if (tid < 8) {
    float a = b2[0];
#pragma unroll
    for (int u2 = 0; u2 < 32; ++u2) a = fmaf(db[tid][u2], W2[u2], a);
    out[b0 + tid] = a;
  }
}

extern "C" void kernel_launch(void* const* d_in, const int* in_sizes, int n_in,
                              void* d_out, int out_size, void* d_ws, size_t ws_size,
                              hipStream_t stream)
{
  const float* x     = (const float*)d_in[0];
  const float* Wih1f = (const float*)d_in[1];
  const float* Whh1f = (const float*)d_in[2];
  const float* bih1f = (const float*)d_in[3];
  const float* bhh1f = (const float*)d_in[4];
  const float* Wih1b = (const float*)d_in[5];
  const float* Whh1b = (const float*)d_in[6];
  const float* bih1b = (const float*)d_in[7];
  const float* bhh1b = (const float*)d_in[8];
  const float* Wih2f = (const float*)d_in[9];
  const float* Whh2f = (const float*)d_in[10];
  const float* bih2f = (const float*)d_in[11];
  const float* bhh2f = (const float*)d_in[12];
  const float* Wih2b = (const float*)d_in[13];
  /* Whh2b (d_in[14]) unused: layer-2 backward at t=T-1 is one step from h=0 */
  const float* bih2b = (const float*)d_in[15];
  const float* bhh2b = (const float*)d_in[16];
  const float* W1    = (const float*)d_in[17];
  const float* b1    = (const float*)d_in[18];
  const float* W2    = (const float*)d_in[19];
  const float* b2    = (const float*)d_in[20];

  (void)d_ws; (void)ws_size; (void)in_sizes; (void)n_in; (void)out_size;

  lstm1_kernel<<<dim3(256, 2), 768, 0, stream>>>(
      x, Wih1f, Whh1f, bih1f, bhh1f, Wih1b, Whh1b, bih1b, bhh1b);
  lstm2f_kernel<<<256, 1024, 0, stream>>>(
      Wih2f, Whh2f, bih2f, bhh2f);
  tail_kernel<<<128, 256, 0, stream>>>(
      Wih2b, bih2b, bhh2b, W1, b1, W2, b2, (float*)d_out);
}

// Round 6
// 11836.433 us; speedup vs baseline: 1.0150x; 1.0150x over previous
//
#include <hip/hip_runtime.h>
#include <math.h>

#define B_  1024
#define T_  512
#define D_  30
#define H1_ 96
#define G1_ 384
#define H2_ 64
#define G2_ 256

// Inter-kernel buffers as device globals (.bss, bound at module load).
// Fully overwritten every call before being read (no cross-call state).
__device__ float g_h1[(size_t)B_ * T_ * 192];   // 384 MiB: layer-1 output
__device__ float g_h2f[(size_t)B_ * H2_];       // layer-2 fwd final state

__device__ __forceinline__ float fast_tanh(float v) {
  float a = fabsf(v);
  float e = __expf(-2.0f * a);
  float t = 1.0f - 2.0f * e / (1.0f + e);
  return v < 0.0f ? -t : t;
}
__device__ __forceinline__ float fast_sigmoid(float v) {
  return 0.5f + 0.5f * fast_tanh(0.5f * v);   // exact identity, overflow-safe
}

#define REP8(M)  M(0) M(1) M(2) M(3) M(4) M(5) M(6) M(7)
#define REP16(M) M(0) M(1) M(2) M(3) M(4) M(5) M(6) M(7) \
                 M(8) M(9) M(10) M(11) M(12) M(13) M(14) M(15)

// ---------------------------------------------------------------------------
// Layer 1: VERBATIM round-3 kernel (benched 2.40 ms, VGPR 72, no spill,
// deterministic). grid (128, 2): 8 batches/block, dir = blockIdx.y.
// 768 threads: (gate g = tid%384, K-half = tid/384), 64 weights/thread in
// 16 named float4. NO waves_per_eu attribute (round-5 lesson: the hint
// doesn't remove a spill, it un-sizes its scratch backing store).
// ---------------------------------------------------------------------------
__global__ __launch_bounds__(768, 3)
void lstm1_kernel(const float* __restrict__ x,
                  const float* __restrict__ Wih_f, const float* __restrict__ Whh_f,
                  const float* __restrict__ bih_f, const float* __restrict__ bhh_f,
                  const float* __restrict__ Wih_b, const float* __restrict__ Whh_b,
                  const float* __restrict__ bih_b, const float* __restrict__ bhh_b)
{
  const int tid = threadIdx.x;
  const int dir = blockIdx.y;
  const int b0  = blockIdx.x * 8;

  const float* __restrict__ Wih = dir ? Wih_b : Wih_f;
  const float* __restrict__ Whh = dir ? Whh_b : Whh_f;
  const float* __restrict__ bih = dir ? bih_b : bih_f;
  const float* __restrict__ bhh = dir ? bhh_b : bhh_f;

  __shared__ __align__(16) float hx[8][128];     // [b][0:30 x | 32:128 h]
  __shared__ float gbuf[G1_ * 17];               // [gate][b*2+half], stride 17

  const int g    = tid % 384;
  const int half = tid / 384;

  float4 w0,w1,w2,w3,w4,w5,w6,w7,w8,w9,w10,w11,w12,w13,w14,w15;
  if (half == 0) {                               // k = 0..63: x-part + h[0:32)
    const float* wr = Wih + g * D_;
    w0 = make_float4(wr[ 0], wr[ 1], wr[ 2], wr[ 3]);
    w1 = make_float4(wr[ 4], wr[ 5], wr[ 6], wr[ 7]);
    w2 = make_float4(wr[ 8], wr[ 9], wr[10], wr[11]);
    w3 = make_float4(wr[12], wr[13], wr[14], wr[15]);
    w4 = make_float4(wr[16], wr[17], wr[18], wr[19]);
    w5 = make_float4(wr[20], wr[21], wr[22], wr[23]);
    w6 = make_float4(wr[24], wr[25], wr[26], wr[27]);
    w7 = make_float4(wr[28], wr[29], 0.0f, 0.0f);
    const float4* hq = (const float4*)(Whh + g * H1_);
    w8 = hq[0]; w9 = hq[1]; w10 = hq[2]; w11 = hq[3];
    w12 = hq[4]; w13 = hq[5]; w14 = hq[6]; w15 = hq[7];
  } else {                                       // k = 64..127: h[32:96)
    const float4* hq = (const float4*)(Whh + g * H1_ + 32);
    w0 = hq[0];  w1 = hq[1];  w2 = hq[2];  w3 = hq[3];
    w4 = hq[4];  w5 = hq[5];  w6 = hq[6];  w7 = hq[7];
    w8 = hq[8];  w9 = hq[9];  w10 = hq[10]; w11 = hq[11];
    w12 = hq[12]; w13 = hq[13]; w14 = hq[14]; w15 = hq[15];
  }

  const int uj = tid % 96;
  const int ub = tid / 96;
  const float bias_i = bih[uj      ] + bhh[uj      ];
  const float bias_f = bih[uj +  96] + bhh[uj +  96];
  const float bias_g = bih[uj + 192] + bhh[uj + 192];
  const float bias_o = bih[uj + 288] + bhh[uj + 288];
  float c_state = 0.0f;

  for (int i = tid; i < 8 * 128; i += 768) (&hx[0][0])[i] = 0.0f;
  __syncthreads();
  const int xb = tid / 30;
  const int xd = tid - xb * 30;
  if (tid < 240) {
    const int t0 = dir ? (T_ - 1) : 0;
    hx[xb][xd] = x[((size_t)(b0 + xb) * T_ + t0) * D_ + xd];
  }
  __syncthreads();

  const int qoff = half * 16;
  const float4* hx4 = (const float4*)(&hx[0][0]);

  for (int s = 0; s < T_; ++s) {
    const int t = dir ? (T_ - 1 - s) : s;
    float xn = 0.0f;
    if (tid < 240 && s + 1 < T_) {
      const int tn = dir ? (t - 1) : (t + 1);
      xn = x[((size_t)(b0 + xb) * T_ + tn) * D_ + xd];
    }
    float acc0 = 0.f, acc1 = 0.f, acc2 = 0.f, acc3 = 0.f;
    float acc4 = 0.f, acc5 = 0.f, acc6 = 0.f, acc7 = 0.f;
#define FB1(i) {                                                              \
    float4 v0 = hx4[0*32 + qoff + i]; float4 v1 = hx4[1*32 + qoff + i];       \
    float4 v2 = hx4[2*32 + qoff + i]; float4 v3 = hx4[3*32 + qoff + i];       \
    float4 v4 = hx4[4*32 + qoff + i]; float4 v5 = hx4[5*32 + qoff + i];       \
    float4 v6 = hx4[6*32 + qoff + i]; float4 v7 = hx4[7*32 + qoff + i];       \
    acc0 = fmaf(w##i.x, v0.x, acc0); acc0 = fmaf(w##i.y, v0.y, acc0);         \
    acc0 = fmaf(w##i.z, v0.z, acc0); acc0 = fmaf(w##i.w, v0.w, acc0);         \
    acc1 = fmaf(w##i.x, v1.x, acc1); acc1 = fmaf(w##i.y, v1.y, acc1);         \
    acc1 = fmaf(w##i.z, v1.z, acc1); acc1 = fmaf(w##i.w, v1.w, acc1);         \
    acc2 = fmaf(w##i.x, v2.x, acc2); acc2 = fmaf(w##i.y, v2.y, acc2);         \
    acc2 = fmaf(w##i.z, v2.z, acc2); acc2 = fmaf(w##i.w, v2.w, acc2);         \
    acc3 = fmaf(w##i.x, v3.x, acc3); acc3 = fmaf(w##i.y, v3.y, acc3);         \
    acc3 = fmaf(w##i.z, v3.z, acc3); acc3 = fmaf(w##i.w, v3.w, acc3);         \
    acc4 = fmaf(w##i.x, v4.x, acc4); acc4 = fmaf(w##i.y, v4.y, acc4);         \
    acc4 = fmaf(w##i.z, v4.z, acc4); acc4 = fmaf(w##i.w, v4.w, acc4);         \
    acc5 = fmaf(w##i.x, v5.x, acc5); acc5 = fmaf(w##i.y, v5.y, acc5);         \
    acc5 = fmaf(w##i.z, v5.z, acc5); acc5 = fmaf(w##i.w, v5.w, acc5);         \
    acc6 = fmaf(w##i.x, v6.x, acc6); acc6 = fmaf(w##i.y, v6.y, acc6);         \
    acc6 = fmaf(w##i.z, v6.z, acc6); acc6 = fmaf(w##i.w, v6.w, acc6);         \
    acc7 = fmaf(w##i.x, v7.x, acc7); acc7 = fmaf(w##i.y, v7.y, acc7);         \
    acc7 = fmaf(w##i.z, v7.z, acc7); acc7 = fmaf(w##i.w, v7.w, acc7); }
    REP16(FB1)
#undef FB1
    {
      const int gb = g * 17 + half;
      gbuf[gb +  0] = acc0; gbuf[gb +  2] = acc1;
      gbuf[gb +  4] = acc2; gbuf[gb +  6] = acc3;
      gbuf[gb +  8] = acc4; gbuf[gb + 10] = acc5;
      gbuf[gb + 12] = acc6; gbuf[gb + 14] = acc7;
    }
    __syncthreads();
    if (tid < 240 && s + 1 < T_) hx[xb][xd] = xn;
    {
      const int ro = ub * 2;
      float gi = gbuf[(uj      ) * 17 + ro] + gbuf[(uj      ) * 17 + ro + 1] + bias_i;
      float gf = gbuf[(uj +  96) * 17 + ro] + gbuf[(uj +  96) * 17 + ro + 1] + bias_f;
      float gg = gbuf[(uj + 192) * 17 + ro] + gbuf[(uj + 192) * 17 + ro + 1] + bias_g;
      float go = gbuf[(uj + 288) * 17 + ro] + gbuf[(uj + 288) * 17 + ro + 1] + bias_o;
      float iv = fast_sigmoid(gi);
      float fv = fast_sigmoid(gf);
      float ov = fast_sigmoid(go);
      c_state = fv * c_state + iv * fast_tanh(gg);
      float h = ov * fast_tanh(c_state);
      hx[ub][32 + uj] = h;
      g_h1[((size_t)(b0 + ub) * T_ + t) * 192 + dir * 96 + uj] = h;
    }
    __syncthreads();
  }
}

// ---------------------------------------------------------------------------
// Layer 2 forward scan v2: g_h1 (B,T,192) -> g_h2f (B,64).
// grid 512: 2 batches/block (2 CU-rounds). 1024 threads: (gate-pair
// p = tid&127 -> gates p and p+128, K-eighth q = tid>>7, K_own=32).
// 64 weight regs (same count as the proven no-spill lstm1 shape), only
// 4 accumulators (2 gates x 2 batches), biases in LDS (bsum) instead of
// 4 resident regs -> hot live set ~80 regs, under the allocator's ~85
// heuristic that round 4 (8 accs + 4 bias regs) tripped into spilling.
// Per-CU DS: 256 b128/step (vs 1024 in round 3).
// ---------------------------------------------------------------------------
__global__ __launch_bounds__(1024)
void lstm2f_kernel(const float* __restrict__ Wih, const float* __restrict__ Whh,
                   const float* __restrict__ bih, const float* __restrict__ bhh)
{
  const int tid = threadIdx.x;
  const int b0  = blockIdx.x * 2;
  const int p   = tid & 127;                     // gate pair: g0=p, g1=p+128
  const int q   = tid >> 7;                      // K-eighth, wave-uniform
  const int g0 = p, g1 = p + 128;

  __shared__ __align__(16) float hx[2][256];     // [b][0:192 h1 | 192:256 h2prev]
  __shared__ float gbuf[G2_ * 17];               // [gate][q*2+b], stride 17
  __shared__ float bsum[G2_];                    // bih+bhh (kept out of VGPRs)

  float4 wa0,wa1,wa2,wa3,wa4,wa5,wa6,wa7;        // gate g0, k=32q..32q+32
  float4 wb0,wb1,wb2,wb3,wb4,wb5,wb6,wb7;        // gate g1
  {
    const float4* A  = (q < 6) ? (const float4*)(Wih + g0 * 192 + 32 * q)
                               : (const float4*)(Whh + g0 * H2_ + 32 * (q - 6));
    const float4* Bp = (q < 6) ? (const float4*)(Wih + g1 * 192 + 32 * q)
                               : (const float4*)(Whh + g1 * H2_ + 32 * (q - 6));
#define LQ2(i) wa##i = A[i]; wb##i = Bp[i];
    REP8(LQ2)
#undef LQ2
  }

  if (tid < 256) bsum[tid] = bih[tid] + bhh[tid];

  const int uj = tid & 63;                       // updaters: tid < 128
  const int ub = (tid >> 6) & 1;
  float c_state = 0.0f;

  for (int i = tid; i < 2 * 256; i += 1024) (&hx[0][0])[i] = 0.0f;
  __syncthreads();
  const int pb = tid / 96;                       // h1 stagers: tid < 192
  const int pj = tid - pb * 96;
  if (tid < 192) {
    *(float2*)&hx[pb][pj * 2] =
        *(const float2*)&g_h1[((size_t)(b0 + pb) * T_ + 0) * 192 + pj * 2];
  }
  __syncthreads();

  const int koff = q * 8;
  const float4* hx4 = (const float4*)(&hx[0][0]);

  for (int s = 0; s < T_; ++s) {
    float2 pre = make_float2(0.0f, 0.0f);
    if (tid < 192 && s + 1 < T_) {
      pre = *(const float2*)&g_h1[((size_t)(b0 + pb) * T_ + (s + 1)) * 192 + pj * 2];
    }
    float a00 = 0.f, a01 = 0.f;                  // gate g0 x batch {0,1}
    float a10 = 0.f, a11 = 0.f;                  // gate g1 x batch {0,1}
#define FB2(i) { \
    float4 v0 = hx4[0*64 + koff + i]; float4 v1 = hx4[1*64 + koff + i]; \
    a00 = fmaf(wa##i.x, v0.x, a00); a00 = fmaf(wa##i.y, v0.y, a00); \
    a00 = fmaf(wa##i.z, v0.z, a00); a00 = fmaf(wa##i.w, v0.w, a00); \
    a01 = fmaf(wa##i.x, v1.x, a01); a01 = fmaf(wa##i.y, v1.y, a01); \
    a01 = fmaf(wa##i.z, v1.z, a01); a01 = fmaf(wa##i.w, v1.w, a01); \
    a10 = fmaf(wb##i.x, v0.x, a10); a10 = fmaf(wb##i.y, v0.y, a10); \
    a10 = fmaf(wb##i.z, v0.z, a10); a10 = fmaf(wb##i.w, v0.w, a10); \
    a11 = fmaf(wb##i.x, v1.x, a11); a11 = fmaf(wb##i.y, v1.y, a11); \
    a11 = fmaf(wb##i.z, v1.z, a11); a11 = fmaf(wb##i.w, v1.w, a11); }
    REP8(FB2)
#undef FB2
    {
      const int e0 = g0 * 17 + q * 2;
      const int e1 = g1 * 17 + q * 2;
      gbuf[e0 + 0] = a00; gbuf[e0 + 1] = a01;
      gbuf[e1 + 0] = a10; gbuf[e1 + 1] = a11;
    }
    __syncthreads();
    if (tid < 192 && s + 1 < T_) *(float2*)&hx[pb][pj * 2] = pre;
    if (tid < 128) {
      float gi = bsum[uj      ];
      float gf = bsum[uj +  64];
      float gg = bsum[uj + 128];
      float go = bsum[uj + 192];
#pragma unroll
      for (int qq = 0; qq < 8; ++qq) {
        gi += gbuf[(uj      ) * 17 + qq * 2 + ub];
        gf += gbuf[(uj +  64) * 17 + qq * 2 + ub];
        gg += gbuf[(uj + 128) * 17 + qq * 2 + ub];
        go += gbuf[(uj + 192) * 17 + qq * 2 + ub];
      }
      float iv = fast_sigmoid(gi), fv = fast_sigmoid(gf), ov = fast_sigmoid(go);
      c_state = fv * c_state + iv * fast_tanh(gg);
      float h = ov * fast_tanh(c_state);
      hx[ub][192 + uj] = h;
      if (s == T_ - 1) g_h2f[(b0 + ub) * H2_ + uj] = h;
    }
    __syncthreads();
  }
}

// ---------------------------------------------------------------------------
// Tail: layer-2 backward (ONE step from zero state on h1[:,T-1,:]) + dense
// head. grid 128 x 256 threads, 8 batch/block. (negligible runtime)
// ---------------------------------------------------------------------------
__global__ __launch_bounds__(256)
void tail_kernel(const float* __restrict__ Wih, const float* __restrict__ bih,
                 const float* __restrict__ bhh,
                 const float* __restrict__ W1, const float* __restrict__ b1,
                 const float* __restrict__ W2, const float* __restrict__ b2,
                 float* __restrict__ out)
{
  const int tid = threadIdx.x;
  const int b0  = blockIdx.x * 8;

  __shared__ __align__(16) float hl[8][192];    // h1 at t = T-1
  __shared__ float gb[G2_ * 9];
  __shared__ __align__(16) float last[8][128];  // [h2f | h2b]
  __shared__ float db[8][32];

  for (int i = tid; i < 8 * 96; i += 256) {
    int bb = i / 96, jj = i - (i / 96) * 96;
    *(float2*)&hl[bb][jj * 2] =
        *(const float2*)&g_h1[((size_t)(b0 + bb) * T_ + (T_ - 1)) * 192 + jj * 2];
  }
  for (int i = tid; i < 8 * 64; i += 256) {
    int bb = i >> 6, jj = i & 63;
    last[bb][jj] = g_h2f[(b0 + bb) * H2_ + jj];
  }
  __syncthreads();

  {
    const int gg_ = tid;
    const float* wr = Wih + gg_ * 192;
    const float bias = bih[gg_] + bhh[gg_];
    float acc[8];
#pragma unroll
    for (int b = 0; b < 8; ++b) acc[b] = bias;
#pragma unroll 4
    for (int qq = 0; qq < 48; ++qq) {
      float4 wv = *(const float4*)&wr[qq * 4];
#pragma unroll
      for (int b = 0; b < 8; ++b) {
        float4 v = *(const float4*)&hl[b][qq * 4];
        acc[b] = fmaf(wv.x, v.x, acc[b]);
        acc[b] = fmaf(wv.y, v.y, acc[b]);
        acc[b] = fmaf(wv.z, v.z, acc[b]);
        acc[b] = fmaf(wv.w, v.w, acc[b]);
      }
    }
#pragma unroll
    for (int b = 0; b < 8; ++b) gb[gg_ * 9 + b] = acc[b];
  }
  __syncthreads();

  for (int pp = tid; pp < 512; pp += 256) {
    int jj = pp & 63, bb = pp >> 6;
    float gi = gb[(jj      ) * 9 + bb];
    float gg = gb[(jj + 128) * 9 + bb];
    float go = gb[(jj + 192) * 9 + bb];
    float c  = fast_sigmoid(gi) * fast_tanh(gg);
    float h  = fast_sigmoid(go) * fast_tanh(c);
    last[bb][64 + jj] = h;
  }
  __syncthreads();

  {
    int u = tid & 31, bb = tid >> 5;
    const float* wr1 = W1 + u * 128;
    float a = b1[u];
#pragma unroll
    for (int qq = 0; qq < 32; ++qq) {
      float4 wv = *(const float4*)&wr1[qq * 4];
      float4 v  = *(const float4*)&last[bb][qq * 4];
      a = fmaf(wv.x, v.x, a); a = fmaf(wv.y, v.y, a);
      a = fmaf(wv.z, v.z, a); a = fmaf(wv.w, v.w, a);
    }
    db[bb][u] = fmaxf(a, 0.0f);
  }
  __syncthreads();

  if (tid < 8) {
    float a = b2[0];
#pragma unroll
    for (int u2 = 0; u2 < 32; ++u2) a = fmaf(db[tid][u2], W2[u2], a);
    out[b0 + tid] = a;
  }
}

extern "C" void kernel_launch(void* const* d_in, const int* in_sizes, int n_in,
                              void* d_out, int out_size, void* d_ws, size_t ws_size,
                              hipStream_t stream)
{
  const float* x     = (const float*)d_in[0];
  const float* Wih1f = (const float*)d_in[1];
  const float* Whh1f = (const float*)d_in[2];
  const float* bih1f = (const float*)d_in[3];
  const float* bhh1f = (const float*)d_in[4];
  const float* Wih1b = (const float*)d_in[5];
  const float* Whh1b = (const float*)d_in[6];
  const float* bih1b = (const float*)d_in[7];
  const float* bhh1b = (const float*)d_in[8];
  const float* Wih2f = (const float*)d_in[9];
  const float* Whh2f = (const float*)d_in[10];
  const float* bih2f = (const float*)d_in[11];
  const float* bhh2f = (const float*)d_in[12];
  const float* Wih2b = (const float*)d_in[13];
  /* Whh2b (d_in[14]) unused: layer-2 backward at t=T-1 is one step from h=0 */
  const float* bih2b = (const float*)d_in[15];
  const float* bhh2b = (const float*)d_in[16];
  const float* W1    = (const float*)d_in[17];
  const float* b1    = (const float*)d_in[18];
  const float* W2    = (const float*)d_in[19];
  const float* b2    = (const float*)d_in[20];

  (void)d_ws; (void)ws_size; (void)in_sizes; (void)n_in; (void)out_size;

  lstm1_kernel<<<dim3(128, 2), 768, 0, stream>>>(
      x, Wih1f, Whh1f, bih1f, bhh1f, Wih1b, Whh1b, bih1b, bhh1b);
  lstm2f_kernel<<<512, 1024, 0, stream>>>(
      Wih2f, Whh2f, bih2f, bhh2f);
  tail_kernel<<<128, 256, 0, stream>>>(
      Wih2b, bih2b, bhh2b, W1, b1, W2, b2, (float*)d_out);
}

// Round 7
// 4563.360 us; speedup vs baseline: 2.6327x; 2.5938x over previous
//
#include <hip/hip_runtime.h>
#include <math.h>

#define B_  1024
#define T_  512
#define D_  30
#define H1_ 96
#define G1_ 384
#define H2_ 64
#define G2_ 256

// Inter-kernel buffers (.bss device globals; fully overwritten every call).
__device__ float g_h1[(size_t)B_ * T_ * 192];    // 384 MiB: layer-1 output
__device__ float g_xw2[(size_t)B_ * T_ * 256];   // 512 MiB: h1@Wih2f^T + biases
__device__ float g_h2f[(size_t)B_ * H2_];        // layer-2 fwd final state

__device__ __forceinline__ float fast_tanh(float v) {
  float a = fabsf(v);
  float e = __expf(-2.0f * a);
  float t = 1.0f - 2.0f * e / (1.0f + e);
  return v < 0.0f ? -t : t;
}
__device__ __forceinline__ float fast_sigmoid(float v) {
  return 0.5f + 0.5f * fast_tanh(0.5f * v);   // exact identity, overflow-safe
}

#define REP8(M)  M(0) M(1) M(2) M(3) M(4) M(5) M(6) M(7)

// ---------------------------------------------------------------------------
// VGPR-cap model (measured r3/r4/r6): backend caps VGPRs at 512/(waves per EU
// at computed occupancy): 768-thr block -> 2 resident -> cap 85 (72 fits, ~95
// spills); 1024-thr -> cap 64. All kernels below designed under these caps.
// ---------------------------------------------------------------------------

// ---------------------------------------------------------------------------
// Layer 1 scan: x (B,T,30) -> g_h1 (B,T,192). grid (512, 2): 2 batches/block,
// dir = blockIdx.y. 768 thr = 192 gate-pairs (g, g+192) x 4 K-splits
// (K_own=32 -> 64 weight regs in 16 named float4). Live ~74 < cap 85.
// v[128]: [0:30)=x_t, [30:32)=0, [32:128)=h_{t-1}. q wave-uniform (192=3 waves).
// ---------------------------------------------------------------------------
__global__ __launch_bounds__(768)
void lstm1_kernel(const float* __restrict__ x,
                  const float* __restrict__ Wih_f, const float* __restrict__ Whh_f,
                  const float* __restrict__ bih_f, const float* __restrict__ bhh_f,
                  const float* __restrict__ Wih_b, const float* __restrict__ Whh_b,
                  const float* __restrict__ bih_b, const float* __restrict__ bhh_b)
{
  const int tid = threadIdx.x;
  const int dir = blockIdx.y;
  const int b0  = blockIdx.x * 2;

  const float* __restrict__ Wih = dir ? Wih_b : Wih_f;
  const float* __restrict__ Whh = dir ? Whh_b : Whh_f;
  const float* __restrict__ bih = dir ? bih_b : bih_f;
  const float* __restrict__ bhh = dir ? bhh_b : bhh_f;

  __shared__ __align__(16) float hx[2][128];   // [b][0:30 x | 32:128 h]
  __shared__ float gbuf[G1_ * 9];              // [gate][q*2+b], stride 9 (odd)
  __shared__ float bsum[G1_];                  // biases out of VGPRs

  const int p = tid % 192;                     // pair: g0=p, g1=p+192
  const int q = tid / 192;                     // K-quarter, wave-uniform
  const int g0 = p, g1 = p + 192;

  float4 wa0,wa1,wa2,wa3,wa4,wa5,wa6,wa7;      // gate g0, k=32q..32q+32
  float4 wb0,wb1,wb2,wb3,wb4,wb5,wb6,wb7;      // gate g1
  if (q == 0) {                                // k 0..31: x-part (30 + 2 zeros)
    const float* A  = Wih + g0 * D_;
    const float* Bp = Wih + g1 * D_;
#define LQ0(i) \
    wa##i = make_float4(A[4*i],  A[4*i+1],  (4*i+2 < 30) ? A[4*i+2]  : 0.f, \
                        (4*i+3 < 30) ? A[4*i+3]  : 0.f); \
    wb##i = make_float4(Bp[4*i], Bp[4*i+1], (4*i+2 < 30) ? Bp[4*i+2] : 0.f, \
                        (4*i+3 < 30) ? Bp[4*i+3] : 0.f);
    REP8(LQ0)
#undef LQ0
  } else {                                     // k 32q..+32 -> h[32(q-1)..]
    const float4* A  = (const float4*)(Whh + g0 * H1_ + 32 * (q - 1));
    const float4* Bp = (const float4*)(Whh + g1 * H1_ + 32 * (q - 1));
#define LQH(i) wa##i = A[i]; wb##i = Bp[i];
    REP8(LQH)
#undef LQH
  }

  if (tid < 384) bsum[tid] = bih[tid] + bhh[tid];

  const int uj = tid % 96;                     // updaters: tid < 192
  const int ub = tid / 96;                     // batch 0/1 for tid<192
  float c_state = 0.0f;

  for (int i = tid; i < 2 * 128; i += 768) (&hx[0][0])[i] = 0.0f;
  __syncthreads();
  const int xb = tid / 30;
  const int xd = tid - xb * 30;
  if (tid < 60) {
    const int t0 = dir ? (T_ - 1) : 0;
    hx[xb][xd] = x[((size_t)(b0 + xb) * T_ + t0) * D_ + xd];
  }
  __syncthreads();

  const int koff = q * 8;
  const float4* hx4 = (const float4*)(&hx[0][0]);

  for (int s = 0; s < T_; ++s) {
    const int t = dir ? (T_ - 1 - s) : s;
    float xn = 0.0f;
    if (tid < 60 && s + 1 < T_) {
      const int tn = dir ? (t - 1) : (t + 1);
      xn = x[((size_t)(b0 + xb) * T_ + tn) * D_ + xd];
    }
    float a00 = 0.f, a01 = 0.f;                // gate g0 x batch {0,1}
    float a10 = 0.f, a11 = 0.f;                // gate g1 x batch {0,1}
#define FB1(i) { \
    float4 v0 = hx4[0*32 + koff + i]; float4 v1 = hx4[1*32 + koff + i]; \
    a00 = fmaf(wa##i.x, v0.x, a00); a00 = fmaf(wa##i.y, v0.y, a00); \
    a00 = fmaf(wa##i.z, v0.z, a00); a00 = fmaf(wa##i.w, v0.w, a00); \
    a01 = fmaf(wa##i.x, v1.x, a01); a01 = fmaf(wa##i.y, v1.y, a01); \
    a01 = fmaf(wa##i.z, v1.z, a01); a01 = fmaf(wa##i.w, v1.w, a01); \
    a10 = fmaf(wb##i.x, v0.x, a10); a10 = fmaf(wb##i.y, v0.y, a10); \
    a10 = fmaf(wb##i.z, v0.z, a10); a10 = fmaf(wb##i.w, v0.w, a10); \
    a11 = fmaf(wb##i.x, v1.x, a11); a11 = fmaf(wb##i.y, v1.y, a11); \
    a11 = fmaf(wb##i.z, v1.z, a11); a11 = fmaf(wb##i.w, v1.w, a11); }
    REP8(FB1)
#undef FB1
    {
      const int e0 = g0 * 9 + q * 2;
      const int e1 = g1 * 9 + q * 2;
      gbuf[e0 + 0] = a00; gbuf[e0 + 1] = a01;
      gbuf[e1 + 0] = a10; gbuf[e1 + 1] = a11;
    }
    __syncthreads();
    if (tid < 60 && s + 1 < T_) hx[xb][xd] = xn;
    if (tid < 192) {
      float gi = bsum[uj      ];
      float gf = bsum[uj +  96];
      float gg = bsum[uj + 192];
      float go = bsum[uj + 288];
#pragma unroll
      for (int qq = 0; qq < 4; ++qq) {
        gi += gbuf[(uj      ) * 9 + qq * 2 + ub];
        gf += gbuf[(uj +  96) * 9 + qq * 2 + ub];
        gg += gbuf[(uj + 192) * 9 + qq * 2 + ub];
        go += gbuf[(uj + 288) * 9 + qq * 2 + ub];
      }
      float iv = fast_sigmoid(gi);
      float fv = fast_sigmoid(gf);
      float ov = fast_sigmoid(go);
      c_state = fv * c_state + iv * fast_tanh(gg);
      float h = ov * fast_tanh(c_state);
      hx[ub][32 + uj] = h;
      g_h1[((size_t)(b0 + ub) * T_ + t) * 192 + dir * 96 + uj] = h;
    }
    __syncthreads();
  }
}

// ---------------------------------------------------------------------------
// xw2 GEMM: g_h1 (B*T, 192) @ Wih2f^T + bih2f + bhh2f -> g_xw2 (B*T, 256).
// Non-recurrent -> plain row-streamed GEMM. grid 512, 768 thr = 128
// gate-pairs (g, g+128) x 6 K-splits (K_own=32 -> 64 w-regs). 2 rows/iter,
// 512 iters/block. Live ~74 < cap 85. q wave-uniform (128 = 2 waves).
// ---------------------------------------------------------------------------
__global__ __launch_bounds__(768)
void xw2_kernel(const float* __restrict__ Wih,
                const float* __restrict__ bih, const float* __restrict__ bhh)
{
  const int tid = threadIdx.x;
  const size_t r0 = (size_t)blockIdx.x * 1024;  // 1024 rows per block
  const int p = tid % 128;
  const int q = tid / 128;                      // 0..5, wave-uniform
  const int g0 = p, g1 = p + 128;

  __shared__ __align__(16) float hrow[2][192];
  __shared__ float gbuf[G2_ * 13];              // [gate][q*2+r], stride 13
  __shared__ float bsum[G2_];

  float4 wa0,wa1,wa2,wa3,wa4,wa5,wa6,wa7;
  float4 wb0,wb1,wb2,wb3,wb4,wb5,wb6,wb7;
  {
    const float4* A  = (const float4*)(Wih + g0 * 192 + 32 * q);
    const float4* Bp = (const float4*)(Wih + g1 * 192 + 32 * q);
#define LQG(i) wa##i = A[i]; wb##i = Bp[i];
    REP8(LQG)
#undef LQG
  }
  if (tid < 256) bsum[tid] = bih[tid] + bhh[tid];

  const int sb = tid / 48, sj = tid % 48;       // row stagers: tid < 96
  if (tid < 96)
    ((float4*)&hrow[0][0])[sb * 48 + sj] =
        ((const float4*)&g_h1[(r0 + sb) * 192])[sj];
  __syncthreads();

  const int koff = q * 8;
  const float4* hr4 = (const float4*)(&hrow[0][0]);

  for (int it = 0; it < 512; ++it) {
    float4 pre;
    if (tid < 96 && it + 1 < 512)
      pre = ((const float4*)&g_h1[(r0 + (size_t)(it + 1) * 2 + sb) * 192])[sj];
    float a00 = 0.f, a01 = 0.f, a10 = 0.f, a11 = 0.f;
#define FB2(i) { \
    float4 v0 = hr4[koff + i]; float4 v1 = hr4[48 + koff + i]; \
    a00 = fmaf(wa##i.x, v0.x, a00); a00 = fmaf(wa##i.y, v0.y, a00); \
    a00 = fmaf(wa##i.z, v0.z, a00); a00 = fmaf(wa##i.w, v0.w, a00); \
    a01 = fmaf(wa##i.x, v1.x, a01); a01 = fmaf(wa##i.y, v1.y, a01); \
    a01 = fmaf(wa##i.z, v1.z, a01); a01 = fmaf(wa##i.w, v1.w, a01); \
    a10 = fmaf(wb##i.x, v0.x, a10); a10 = fmaf(wb##i.y, v0.y, a10); \
    a10 = fmaf(wb##i.z, v0.z, a10); a10 = fmaf(wb##i.w, v0.w, a10); \
    a11 = fmaf(wb##i.x, v1.x, a11); a11 = fmaf(wb##i.y, v1.y, a11); \
    a11 = fmaf(wb##i.z, v1.z, a11); a11 = fmaf(wb##i.w, v1.w, a11); }
    REP8(FB2)
#undef FB2
    {
      const int e0 = g0 * 13 + q * 2;
      const int e1 = g1 * 13 + q * 2;
      gbuf[e0 + 0] = a00; gbuf[e0 + 1] = a01;
      gbuf[e1 + 0] = a10; gbuf[e1 + 1] = a11;
    }
    __syncthreads();
    if (tid < 96 && it + 1 < 512)
      ((float4*)&hrow[0][0])[sb * 48 + sj] = pre;
    if (tid < 512) {
      const int r = tid >> 8, g = tid & 255;
      float a = bsum[g];
#pragma unroll
      for (int qq = 0; qq < 6; ++qq) a += gbuf[g * 13 + qq * 2 + r];
      g_xw2[(r0 + (size_t)it * 2 + r) * 256 + g] = a;
    }
    __syncthreads();
  }
}

// ---------------------------------------------------------------------------
// Layer 2 forward scan (K=64 recurrent only): gates = xw2[t] + h2@Whh^T.
// grid 256: 4 batches/block, 1 block/CU. 1024 thr = 128 gate-pairs x 8
// K-splits (K_own=8 -> 16 w-regs; live ~40 < cap 64). xw2 double-buffered.
// ---------------------------------------------------------------------------
__global__ __launch_bounds__(1024)
void lstm2f_kernel(const float* __restrict__ Whh)
{
  const int tid = threadIdx.x;
  const int b0  = blockIdx.x * 4;
  const int p   = tid % 128;
  const int q   = tid / 128;                   // 0..7, wave-uniform
  const int g0 = p, g1 = p + 128;

  __shared__ __align__(16) float h2[4][64];
  __shared__ float gbuf[G2_ * 33];             // [gate][q*4+b], stride 33
  __shared__ float xwb[2][4 * 256];            // double-buffered xw2 rows

  float4 wa0, wa1, wb0, wb1;                   // k = 8q..8q+8
  {
    const float4* A  = (const float4*)(Whh + g0 * H2_ + 8 * q);
    const float4* Bp = (const float4*)(Whh + g1 * H2_ + 8 * q);
    wa0 = A[0]; wa1 = A[1]; wb0 = Bp[0]; wb1 = Bp[1];
  }

  const int uj = tid & 63;                     // updaters: tid < 256
  const int ub = (tid >> 6) & 3;
  float c_state = 0.0f;

  if (tid < 256) (&h2[0][0])[tid] = 0.0f;
  xwb[0][tid] = g_xw2[((size_t)(b0 + (tid >> 8)) * T_ + 0) * 256 + (tid & 255)];
  __syncthreads();

  const int koff = q * 2;
  const float4* h24 = (const float4*)(&h2[0][0]);
  int cur = 0;

  for (int s = 0; s < T_; ++s) {
    float xn = 0.0f;
    if (s + 1 < T_)
      xn = g_xw2[((size_t)(b0 + (tid >> 8)) * T_ + (s + 1)) * 256 + (tid & 255)];
    float a00 = 0.f, a01 = 0.f, a02 = 0.f, a03 = 0.f;
    float a10 = 0.f, a11 = 0.f, a12 = 0.f, a13 = 0.f;
#define FB3(i) { \
    float4 v0 = h24[ 0 + koff + i]; float4 v1 = h24[16 + koff + i]; \
    float4 v2 = h24[32 + koff + i]; float4 v3 = h24[48 + koff + i]; \
    a00 = fmaf(wa##i.x, v0.x, a00); a00 = fmaf(wa##i.y, v0.y, a00); \
    a00 = fmaf(wa##i.z, v0.z, a00); a00 = fmaf(wa##i.w, v0.w, a00); \
    a01 = fmaf(wa##i.x, v1.x, a01); a01 = fmaf(wa##i.y, v1.y, a01); \
    a01 = fmaf(wa##i.z, v1.z, a01); a01 = fmaf(wa##i.w, v1.w, a01); \
    a02 = fmaf(wa##i.x, v2.x, a02); a02 = fmaf(wa##i.y, v2.y, a02); \
    a02 = fmaf(wa##i.z, v2.z, a02); a02 = fmaf(wa##i.w, v2.w, a02); \
    a03 = fmaf(wa##i.x, v3.x, a03); a03 = fmaf(wa##i.y, v3.y, a03); \
    a03 = fmaf(wa##i.z, v3.z, a03); a03 = fmaf(wa##i.w, v3.w, a03); \
    a10 = fmaf(wb##i.x, v0.x, a10); a10 = fmaf(wb##i.y, v0.y, a10); \
    a10 = fmaf(wb##i.z, v0.z, a10); a10 = fmaf(wb##i.w, v0.w, a10); \
    a11 = fmaf(wb##i.x, v1.x, a11); a11 = fmaf(wb##i.y, v1.y, a11); \
    a11 = fmaf(wb##i.z, v1.z, a11); a11 = fmaf(wb##i.w, v1.w, a11); \
    a12 = fmaf(wb##i.x, v2.x, a12); a12 = fmaf(wb##i.y, v2.y, a12); \
    a12 = fmaf(wb##i.z, v2.z, a12); a12 = fmaf(wb##i.w, v2.w, a12); \
    a13 = fmaf(wb##i.x, v3.x, a13); a13 = fmaf(wb##i.y, v3.y, a13); \
    a13 = fmaf(wb##i.z, v3.z, a13); a13 = fmaf(wb##i.w, v3.w, a13); }
    FB3(0) FB3(1)
#undef FB3
    {
      const int e0 = g0 * 33 + q * 4;
      const int e1 = g1 * 33 + q * 4;
      gbuf[e0+0] = a00; gbuf[e0+1] = a01; gbuf[e0+2] = a02; gbuf[e0+3] = a03;
      gbuf[e1+0] = a10; gbuf[e1+1] = a11; gbuf[e1+2] = a12; gbuf[e1+3] = a13;
    }
    __syncthreads();
    if (s + 1 < T_) xwb[cur ^ 1][tid] = xn;
    if (tid < 256) {
      float gi = xwb[cur][ub * 256 + uj      ];
      float gf = xwb[cur][ub * 256 + uj +  64];
      float gg = xwb[cur][ub * 256 + uj + 128];
      float go = xwb[cur][ub * 256 + uj + 192];
#pragma unroll
      for (int qq = 0; qq < 8; ++qq) {
        gi += gbuf[(uj      ) * 33 + qq * 4 + ub];
        gf += gbuf[(uj +  64) * 33 + qq * 4 + ub];
        gg += gbuf[(uj + 128) * 33 + qq * 4 + ub];
        go += gbuf[(uj + 192) * 33 + qq * 4 + ub];
      }
      float iv = fast_sigmoid(gi), fv = fast_sigmoid(gf), ov = fast_sigmoid(go);
      c_state = fv * c_state + iv * fast_tanh(gg);
      float h = ov * fast_tanh(c_state);
      h2[ub][uj] = h;
      if (s == T_ - 1) g_h2f[(b0 + ub) * H2_ + uj] = h;
    }
    __syncthreads();
    cur ^= 1;
  }
}

// ---------------------------------------------------------------------------
// Tail: layer-2 backward (ONE step from zero state on h1[:,T-1,:]) + dense
// head. grid 128 x 256 threads, 8 batch/block. (negligible runtime)
// ---------------------------------------------------------------------------
__global__ __launch_bounds__(256)
void tail_kernel(const float* __restrict__ Wih, const float* __restrict__ bih,
                 const float* __restrict__ bhh,
                 const float* __restrict__ W1, const float* __restrict__ b1,
                 const float* __restrict__ W2, const float* __restrict__ b2,
                 float* __restrict__ out)
{
  const int tid = threadIdx.x;
  const int b0  = blockIdx.x * 8;

  __shared__ __align__(16) float hl[8][192];    // h1 at t = T-1
  __shared__ float gb[G2_ * 9];
  __shared__ __align__(16) float last[8][128];  // [h2f | h2b]
  __shared__ float db[8][32];

  for (int i = tid; i < 8 * 96; i += 256) {
    int bb = i / 96, jj = i - (i / 96) * 96;
    *(float2*)&hl[bb][jj * 2] =
        *(const float2*)&g_h1[((size_t)(b0 + bb) * T_ + (T_ - 1)) * 192 + jj * 2];
  }
  for (int i = tid; i < 8 * 64; i += 256) {
    int bb = i >> 6, jj = i & 63;
    last[bb][jj] = g_h2f[(b0 + bb) * H2_ + jj];
  }
  __syncthreads();

  {
    const int gg_ = tid;
    const float* wr = Wih + gg_ * 192;
    const float bias = bih[gg_] + bhh[gg_];
    float acc[8];
#pragma unroll
    for (int b = 0; b < 8; ++b) acc[b] = bias;
#pragma unroll 4
    for (int qq = 0; qq < 48; ++qq) {
      float4 wv = *(const float4*)&wr[qq * 4];
#pragma unroll
      for (int b = 0; b < 8; ++b) {
        float4 v = *(const float4*)&hl[b][qq * 4];
        acc[b] = fmaf(wv.x, v.x, acc[b]);
        acc[b] = fmaf(wv.y, v.y, acc[b]);
        acc[b] = fmaf(wv.z, v.z, acc[b]);
        acc[b] = fmaf(wv.w, v.w, acc[b]);
      }
    }
#pragma unroll
    for (int b = 0; b < 8; ++b) gb[gg_ * 9 + b] = acc[b];
  }
  __syncthreads();

  for (int pp = tid; pp < 512; pp += 256) {
    int jj = pp & 63, bb = pp >> 6;
    float gi = gb[(jj      ) * 9 + bb];
    float gg = gb[(jj + 128) * 9 + bb];
    float go = gb[(jj + 192) * 9 + bb];
    float c  = fast_sigmoid(gi) * fast_tanh(gg);
    float h  = fast_sigmoid(go) * fast_tanh(c);
    last[bb][64 + jj] = h;
  }
  __syncthreads();

  {
    int u = tid & 31, bb = tid >> 5;
    const float* wr1 = W1 + u * 128;
    float a = b1[u];
#pragma unroll
    for (int qq = 0; qq < 32; ++qq) {
      float4 wv = *(const float4*)&wr1[qq * 4];
      float4 v  = *(const float4*)&last[bb][qq * 4];
      a = fmaf(wv.x, v.x, a); a = fmaf(wv.y, v.y, a);
      a = fmaf(wv.z, v.z, a); a = fmaf(wv.w, v.w, a);
    }
    db[bb][u] = fmaxf(a, 0.0f);
  }
  __syncthreads();

  if (tid < 8) {
    float a = b2[0];
#pragma unroll
    for (int u2 = 0; u2 < 32; ++u2) a = fmaf(db[tid][u2], W2[u2], a);
    out[b0 + tid] = a;
  }
}

extern "C" void kernel_launch(void* const* d_in, const int* in_sizes, int n_in,
                              void* d_out, int out_size, void* d_ws, size_t ws_size,
                              hipStream_t stream)
{
  const float* x     = (const float*)d_in[0];
  const float* Wih1f = (const float*)d_in[1];
  const float* Whh1f = (const float*)d_in[2];
  const float* bih1f = (const float*)d_in[3];
  const float* bhh1f = (const float*)d_in[4];
  const float* Wih1b = (const float*)d_in[5];
  const float* Whh1b = (const float*)d_in[6];
  const float* bih1b = (const float*)d_in[7];
  const float* bhh1b = (const float*)d_in[8];
  const float* Wih2f = (const float*)d_in[9];
  const float* Whh2f = (const float*)d_in[10];
  const float* bih2f = (const float*)d_in[11];
  const float* bhh2f = (const float*)d_in[12];
  const float* Wih2b = (const float*)d_in[13];
  /* Whh2b (d_in[14]) unused: layer-2 backward at t=T-1 is one step from h=0 */
  const float* bih2b = (const float*)d_in[15];
  const float* bhh2b = (const float*)d_in[16];
  const float* W1    = (const float*)d_in[17];
  const float* b1    = (const float*)d_in[18];
  const float* W2    = (const float*)d_in[19];
  const float* b2    = (const float*)d_in[20];

  (void)d_ws; (void)ws_size; (void)in_sizes; (void)n_in; (void)out_size;

  lstm1_kernel<<<dim3(512, 2), 768, 0, stream>>>(
      x, Wih1f, Whh1f, bih1f, bhh1f, Wih1b, Whh1b, bih1b, bhh1b);
  xw2_kernel<<<512, 768, 0, stream>>>(Wih2f, bih2f, bhh2f);
  lstm2f_kernel<<<256, 1024, 0, stream>>>(Whh2f);
  tail_kernel<<<128, 256, 0, stream>>>(
      Wih2b, bih2b, bhh2b, W1, b1, W2, b2, (float*)d_out);
}